// Round 8
// baseline (107.947 us; speedup 1.0000x reference)
//
#include <hip/hip_runtime.h>
#include <math.h>

// Exact fusion of: resize(256->1024) -> warp_perspective(affine) -> resize(1024->256).
// Round-8 (measurement + locality):
//  * XCD swizzle: dispatch-linear block id n -> xcd = n&7 owns images
//    b in {2*xcd, 2*xcd+1}; per-XCD L2 working set drops 12.6 MB -> ~1.6 MB
//    (L2-resident gathers instead of L3).
//  * The kernel is launched TWICE (idempotent, identical work every call) so
//    dur_us - dur_R7 isolates the kernel's true time from harness overhead.
// Math identical to round 7 (absmax preserved).

typedef float floatx4 __attribute__((ext_vector_type(4)));

__device__ __forceinline__ floatx4 load4(const float* p) {
    floatx4 v;
    __builtin_memcpy(&v, p, sizeof(v));  // 4B-aligned 16B load -> dwordx4
    return v;
}

struct Up { int i0; float w; };

__device__ __forceinline__ Up upc(int v) {
    float u = fmaf(0.25f, (float)v, -0.375f);
    u = fminf(fmaxf(u, 0.0f), 255.0f);
    float f = floorf(u);
    Up r; r.i0 = (int)f; r.w = u - f;
    return r;
}

struct Trip { float w0, w1, w2; int base; };

__device__ __forceinline__ Trip merged3(float s) {
    float f = floorf(s);
    float fr = s - f;
    int v0 = (int)f;
    int v1 = min(v0 + 1, 1023);
    Up c0 = upc(v0), c1 = upc(v1);
    float A0 = 1.0f - fr, A1 = fr;
    float b0 = A1 * (1.0f - c1.w), b1 = A1 * c1.w;
    bool d = (c1.i0 != c0.i0);
    Trip t;
    t.w0 = A0 * (1.0f - c0.w) + (d ? 0.0f : b0);
    t.w1 = A0 * c0.w + (d ? b0 : b1);
    t.w2 = d ? b1 : 0.0f;
    t.base = c0.i0;
    return t;
}

// Exact round-4 pair accumulation (fallback for rare wide-spread threads).
__device__ __forceinline__ void pair_accum(
    Trip cA, Trip cB, Trip rA, Trip rB,
    const float* __restrict__ xb, float* acc)
{
    int cb = min(cA.base, cB.base);
    int rb = min(rA.base, rB.base);
    float CA[4], CB[4], RA[4], RB[4];
    bool sa_ = (cA.base != cb);
    CA[0] = sa_ ? 0.f : cA.w0;  CA[1] = sa_ ? cA.w0 : cA.w1;
    CA[2] = sa_ ? cA.w1 : cA.w2;  CA[3] = sa_ ? cA.w2 : 0.f;
    bool sb_ = (cB.base != cb);
    CB[0] = sb_ ? 0.f : cB.w0;  CB[1] = sb_ ? cB.w0 : cB.w1;
    CB[2] = sb_ ? cB.w1 : cB.w2;  CB[3] = sb_ ? cB.w2 : 0.f;
    bool ra_ = (rA.base != rb);
    RA[0] = ra_ ? 0.f : rA.w0;  RA[1] = ra_ ? rA.w0 : rA.w1;
    RA[2] = ra_ ? rA.w1 : rA.w2;  RA[3] = ra_ ? rA.w2 : 0.f;
    bool rb_ = (rB.base != rb);
    RB[0] = rb_ ? 0.f : rB.w0;  RB[1] = rb_ ? rB.w0 : rB.w1;
    RB[2] = rb_ ? rB.w1 : rB.w2;  RB[3] = rb_ ? rB.w2 : 0.f;

    float W[4][4];
#pragma unroll
    for (int r = 0; r < 4; ++r)
#pragma unroll
        for (int c = 0; c < 4; ++c)
            W[r][c] = fmaf(RB[r], CB[c], RA[r] * CA[c]);

    int base = cb;
    if (cb > 252) {
        int shift = cb - 252;
        base = 252;
        for (int s = 0; s < shift; ++s) {
#pragma unroll
            for (int r = 0; r < 4; ++r) {
                W[r][3] = W[r][2]; W[r][2] = W[r][1];
                W[r][1] = W[r][0]; W[r][0] = 0.f;
            }
        }
    }
    int e0 = rb * 256 + base;
    int e1 = min(rb + 1, 255) * 256 + base;
    int e2 = min(rb + 2, 255) * 256 + base;
    int e3 = min(rb + 3, 255) * 256 + base;
#pragma unroll
    for (int ch = 0; ch < 3; ++ch) {
        const float* pc = xb + ch * 65536;
        floatx4 L0 = load4(pc + e0);
        floatx4 L1 = load4(pc + e1);
        floatx4 L2 = load4(pc + e2);
        floatx4 L3 = load4(pc + e3);
        float s0 = fmaf(W[0][3], L0.w, fmaf(W[0][2], L0.z, fmaf(W[0][1], L0.y, W[0][0] * L0.x)));
        float s1 = fmaf(W[1][3], L1.w, fmaf(W[1][2], L1.z, fmaf(W[1][1], L1.y, W[1][0] * L1.x)));
        float s2 = fmaf(W[2][3], L2.w, fmaf(W[2][2], L2.z, fmaf(W[2][1], L2.y, W[2][0] * L2.x)));
        float s3 = fmaf(W[3][3], L3.w, fmaf(W[3][2], L3.z, fmaf(W[3][1], L3.y, W[3][0] * L3.x)));
        acc[ch] += (s0 + s1) + (s2 + s3);
    }
}

__global__ __launch_bounds__(256) void fused_warp(
    const float* __restrict__ x,
    const float* __restrict__ paramP, const float* __restrict__ paramM,
    const float* __restrict__ gumbel_u, const float* __restrict__ eps,
    const int* __restrict__ idx,
    float* __restrict__ out, int N)
{
    __shared__ float smem[8];

    // ---- XCD swizzle: dispatch-linear id n (x fastest); n%8 ~ XCD.
    // Each XCD owns 2 images; tiles enumerate within.
    int lin = (blockIdx.z * 16 + blockIdx.y) * 16 + blockIdx.x;
    int xcd  = lin & 7;
    int rest = lin >> 3;
    int b  = 2 * xcd + (rest & 1);
    int t  = rest >> 1;          // [0,256)
    int tx = t & 15;
    int ty = t >> 4;

    int tid = threadIdx.y * 16 + threadIdx.x;

    // ---- per-block inverse-matrix computation (wave 0 only) ----
    if (tid < 64) {
        float dec = 0.f, sMv = 0.f;
        if (tid < 7) {
            int k = tid;
            int id = idx[b];
            float vP = paramP[k * N + id];
            float pP = 1.0f / (1.0f + expf(-vP));
            float l0 = logf(pP);
            float l1 = logf(1.0f - pP);
            float u0 = gumbel_u[(k * 16 + b) * 2 + 0];
            float u1 = gumbel_u[(k * 16 + b) * 2 + 1];
            float g0 = -logf(-logf(u0));
            float g1 = -logf(-logf(u1));
            dec = (l0 + g0 >= l1 + g1) ? 1.0f : 0.0f;  // argmax tie -> index 0
            float vM = paramM[k * N + id];
            float sig = 1.0f / (1.0f + expf(-vM));
            sMv = sig * eps[k * 16 + b];
        }
        float sP[7], sM[7];
#pragma unroll
        for (int k = 0; k < 7; ++k) {
            sP[k] = __shfl(dec, k, 64);
            sM[k] = __shfl(sMv, k, 64);
        }
        if (tid == 0) {
            float ang = sP[0] * sM[0] * 30.0f;
            float rad = ang * 0.017453292519943295f;
            float ca = cosf(rad), sa = sinf(rad);
            float sx = 1.0f + sP[5] * sM[5] * 0.5f;
            float sy = 1.0f + sP[6] * sM[6] * 0.5f;
            float sr00 = ca * sx, sr01 = sa * sy;
            float sr10 = -sa * sx, sr11 = ca * sy;
            float t0 = 128.0f - (sr00 + sr01) * 128.0f;
            float t1 = 128.0f - (sr10 + sr11) * 128.0f;
            float tx2 = 256.0f * sP[1] * sM[1] * 0.45f;
            float ty2 = 256.0f * sP[2] * sM[2] * 0.45f;
            float sh01 = sP[3] * sM[3] * 0.3f;
            float sh10 = sP[4] * sM[4] * 0.3f;
            float e0 = t0 + tx2, e1 = t1 + ty2;
            float a  = sr00 + sh01 * sr10;
            float bb = sr01 + sh01 * sr11;
            float txm = e0 + sh01 * e1;
            float c  = sh10 * sr00 + sr10;
            float d  = sh10 * sr01 + sr11;
            float tym = sh10 * e0 + e1;
            float det = a * d - bb * c;
            float rdet = 1.0f / det;
            smem[0] = d * rdet;
            smem[1] = -bb * rdet;
            smem[2] = (bb * tym - d * txm) * rdet;
            smem[3] = -c * rdet;
            smem[4] = a * rdet;
            smem[5] = (c * txm - a * tym) * rdet;
        }
    }
    __syncthreads();

    float m00 = smem[0], m01 = smem[1], m02 = smem[2];
    float m10 = smem[3], m11 = smem[4], m12 = smem[5];

    int j = tx * 16 + threadIdx.x;
    int i = ty * 16 + threadIdx.y;
    const float* xb = x + b * 3 * 65536;

    float XA = (float)(4 * j + 1);
    float Y0 = (float)(4 * i + 1);
    float x0 = fmaf(m00, XA, fmaf(m01, Y0, m02));
    float y0 = fmaf(m10, XA, fmaf(m11, Y0, m12));
    float xs[4], ys[4];
    xs[0] = x0;        ys[0] = y0;
    xs[1] = x0 + m00;  ys[1] = y0 + m10;
    xs[2] = x0 + m01;  ys[2] = y0 + m11;
    xs[3] = xs[1] + m01; ys[3] = ys[1] + m11;

    Trip cx[4], ry[4];
#pragma unroll
    for (int s = 0; s < 4; ++s) {
        cx[s] = merged3(fminf(fmaxf(xs[s], 0.f), 1023.f));
        ry[s] = merged3(fminf(fmaxf(ys[s], 0.f), 1023.f));
    }

    int cbmin = min(min(cx[0].base, cx[1].base), min(cx[2].base, cx[3].base));
    int cbmax = max(max(cx[0].base, cx[1].base), max(cx[2].base, cx[3].base));
    int rbmin = min(min(ry[0].base, ry[1].base), min(ry[2].base, ry[3].base));
    int rbmax = max(max(ry[0].base, ry[1].base), max(ry[2].base, ry[3].base));

    float acc[3] = {0.f, 0.f, 0.f};

    if (((cbmax - cbmin) | (rbmax - rbmin)) <= 1) {
        // ---- fast path: single 4x4 union window, W = sum of 4 outer products
        float W[4][4];
#pragma unroll
        for (int s = 0; s < 4; ++s) {
            bool sc = (cx[s].base != cbmin);
            float C0 = sc ? 0.f : cx[s].w0;
            float C1 = sc ? cx[s].w0 : cx[s].w1;
            float C2 = sc ? cx[s].w1 : cx[s].w2;
            float C3 = sc ? cx[s].w2 : 0.f;
            bool sr = (ry[s].base != rbmin);
            float R0 = sr ? 0.f : ry[s].w0;
            float R1 = sr ? ry[s].w0 : ry[s].w1;
            float R2 = sr ? ry[s].w1 : ry[s].w2;
            float R3 = sr ? ry[s].w2 : 0.f;
            float C[4] = {C0, C1, C2, C3};
            float R[4] = {R0, R1, R2, R3};
            if (s == 0) {
#pragma unroll
                for (int r = 0; r < 4; ++r)
#pragma unroll
                    for (int c = 0; c < 4; ++c)
                        W[r][c] = R[r] * C[c];
            } else {
#pragma unroll
                for (int r = 0; r < 4; ++r)
#pragma unroll
                    for (int c = 0; c < 4; ++c)
                        W[r][c] = fmaf(R[r], C[c], W[r][c]);
            }
        }

        int base = cbmin;
        if (cbmin > 252) {
            int shift = cbmin - 252;
            base = 252;
            for (int s = 0; s < shift; ++s) {
#pragma unroll
                for (int r = 0; r < 4; ++r) {
                    W[r][3] = W[r][2]; W[r][2] = W[r][1];
                    W[r][1] = W[r][0]; W[r][0] = 0.f;
                }
            }
        }

        int e0 = rbmin * 256 + base;
        int e1 = min(rbmin + 1, 255) * 256 + base;
        int e2 = min(rbmin + 2, 255) * 256 + base;
        int e3 = min(rbmin + 3, 255) * 256 + base;
#pragma unroll
        for (int ch = 0; ch < 3; ++ch) {
            const float* pc = xb + ch * 65536;
            floatx4 L0 = load4(pc + e0);
            floatx4 L1 = load4(pc + e1);
            floatx4 L2 = load4(pc + e2);
            floatx4 L3 = load4(pc + e3);
            float s0 = fmaf(W[0][3], L0.w, fmaf(W[0][2], L0.z, fmaf(W[0][1], L0.y, W[0][0] * L0.x)));
            float s1 = fmaf(W[1][3], L1.w, fmaf(W[1][2], L1.z, fmaf(W[1][1], L1.y, W[1][0] * L1.x)));
            float s2 = fmaf(W[2][3], L2.w, fmaf(W[2][2], L2.z, fmaf(W[2][1], L2.y, W[2][0] * L2.x)));
            float s3 = fmaf(W[3][3], L3.w, fmaf(W[3][2], L3.z, fmaf(W[3][1], L3.y, W[3][0] * L3.x)));
            acc[ch] = (s0 + s1) + (s2 + s3);
        }
    } else {
        pair_accum(cx[0], cx[1], ry[0], ry[1], xb, acc);
        pair_accum(cx[2], cx[3], ry[2], ry[3], xb, acc);
    }

    int obase = ((b * 3) * 256 + i) * 256 + j;
    out[obase]          = 0.25f * acc[0];
    out[obase + 65536]  = 0.25f * acc[1];
    out[obase + 131072] = 0.25f * acc[2];
}

extern "C" void kernel_launch(void* const* d_in, const int* in_sizes, int n_in,
                              void* d_out, int out_size, void* d_ws, size_t ws_size,
                              hipStream_t stream) {
    const float* x      = (const float*)d_in[0];
    const float* paramP = (const float*)d_in[1];
    const float* paramM = (const float*)d_in[2];
    const float* gumbel = (const float*)d_in[3];
    const float* eps    = (const float*)d_in[4];
    const int*   idx    = (const int*)d_in[5];
    float* out = (float*)d_out;
    int N = in_sizes[1] / 7;

    // Launched twice on purpose (idempotent): dur_R8 - dur_R7 isolates the
    // kernel's wall time from the fixed harness overhead (poison fills +
    // restores), which profiling cannot see (kernel below top-5 cutoff).
    hipLaunchKernelGGL(fused_warp, dim3(16, 16, 16), dim3(16, 16, 1), 0, stream,
                       x, paramP, paramM, gumbel, eps, idx, out, N);
    hipLaunchKernelGGL(fused_warp, dim3(16, 16, 16), dim3(16, 16, 1), 0, stream,
                       x, paramP, paramM, gumbel, eps, idx, out, N);
}

// Round 9
// 87.476 us; speedup vs baseline: 1.2340x; 1.2340x over previous
//
#include <hip/hip_runtime.h>
#include <math.h>

// Exact fusion of: resize(256->1024) -> warp_perspective(affine) -> resize(1024->256).
// Round-9: 8x8 wave tiling. Each 64-lane wave covers an 8x8 output sub-tile
// (waves arranged 2x2 inside the 16x16 block tile) so the wave's source
// footprint is a compact ~11x11 coarse-px bbox (~22 L1 lines/instruction)
// instead of the 16x4 strip (~40+ lines/instruction). The kernel is L1
// line-lookup bound (R8 dual-launch isolated kernel ~20us; VALU only ~6us).
// Math identical to round 7 (absmax preserved).

typedef float floatx4 __attribute__((ext_vector_type(4)));

__device__ __forceinline__ floatx4 load4(const float* p) {
    floatx4 v;
    __builtin_memcpy(&v, p, sizeof(v));  // 4B-aligned 16B load -> dwordx4
    return v;
}

struct Up { int i0; float w; };

__device__ __forceinline__ Up upc(int v) {
    float u = fmaf(0.25f, (float)v, -0.375f);
    u = fminf(fmaxf(u, 0.0f), 255.0f);
    float f = floorf(u);
    Up r; r.i0 = (int)f; r.w = u - f;
    return r;
}

struct Trip { float w0, w1, w2; int base; };

__device__ __forceinline__ Trip merged3(float s) {
    float f = floorf(s);
    float fr = s - f;
    int v0 = (int)f;
    int v1 = min(v0 + 1, 1023);
    Up c0 = upc(v0), c1 = upc(v1);
    float A0 = 1.0f - fr, A1 = fr;
    float b0 = A1 * (1.0f - c1.w), b1 = A1 * c1.w;
    bool d = (c1.i0 != c0.i0);
    Trip t;
    t.w0 = A0 * (1.0f - c0.w) + (d ? 0.0f : b0);
    t.w1 = A0 * c0.w + (d ? b0 : b1);
    t.w2 = d ? b1 : 0.0f;
    t.base = c0.i0;
    return t;
}

// Exact round-4 pair accumulation (fallback for rare wide-spread threads).
__device__ __forceinline__ void pair_accum(
    Trip cA, Trip cB, Trip rA, Trip rB,
    const float* __restrict__ xb, float* acc)
{
    int cb = min(cA.base, cB.base);
    int rb = min(rA.base, rB.base);
    float CA[4], CB[4], RA[4], RB[4];
    bool sa_ = (cA.base != cb);
    CA[0] = sa_ ? 0.f : cA.w0;  CA[1] = sa_ ? cA.w0 : cA.w1;
    CA[2] = sa_ ? cA.w1 : cA.w2;  CA[3] = sa_ ? cA.w2 : 0.f;
    bool sb_ = (cB.base != cb);
    CB[0] = sb_ ? 0.f : cB.w0;  CB[1] = sb_ ? cB.w0 : cB.w1;
    CB[2] = sb_ ? cB.w1 : cB.w2;  CB[3] = sb_ ? cB.w2 : 0.f;
    bool ra_ = (rA.base != rb);
    RA[0] = ra_ ? 0.f : rA.w0;  RA[1] = ra_ ? rA.w0 : rA.w1;
    RA[2] = ra_ ? rA.w1 : rA.w2;  RA[3] = ra_ ? rA.w2 : 0.f;
    bool rb_ = (rB.base != rb);
    RB[0] = rb_ ? 0.f : rB.w0;  RB[1] = rb_ ? rB.w0 : rB.w1;
    RB[2] = rb_ ? rB.w1 : rB.w2;  RB[3] = rb_ ? rB.w2 : 0.f;

    float W[4][4];
#pragma unroll
    for (int r = 0; r < 4; ++r)
#pragma unroll
        for (int c = 0; c < 4; ++c)
            W[r][c] = fmaf(RB[r], CB[c], RA[r] * CA[c]);

    int base = cb;
    if (cb > 252) {
        int shift = cb - 252;
        base = 252;
        for (int s = 0; s < shift; ++s) {
#pragma unroll
            for (int r = 0; r < 4; ++r) {
                W[r][3] = W[r][2]; W[r][2] = W[r][1];
                W[r][1] = W[r][0]; W[r][0] = 0.f;
            }
        }
    }
    int e0 = rb * 256 + base;
    int e1 = min(rb + 1, 255) * 256 + base;
    int e2 = min(rb + 2, 255) * 256 + base;
    int e3 = min(rb + 3, 255) * 256 + base;
#pragma unroll
    for (int ch = 0; ch < 3; ++ch) {
        const float* pc = xb + ch * 65536;
        floatx4 L0 = load4(pc + e0);
        floatx4 L1 = load4(pc + e1);
        floatx4 L2 = load4(pc + e2);
        floatx4 L3 = load4(pc + e3);
        float s0 = fmaf(W[0][3], L0.w, fmaf(W[0][2], L0.z, fmaf(W[0][1], L0.y, W[0][0] * L0.x)));
        float s1 = fmaf(W[1][3], L1.w, fmaf(W[1][2], L1.z, fmaf(W[1][1], L1.y, W[1][0] * L1.x)));
        float s2 = fmaf(W[2][3], L2.w, fmaf(W[2][2], L2.z, fmaf(W[2][1], L2.y, W[2][0] * L2.x)));
        float s3 = fmaf(W[3][3], L3.w, fmaf(W[3][2], L3.z, fmaf(W[3][1], L3.y, W[3][0] * L3.x)));
        acc[ch] += (s0 + s1) + (s2 + s3);
    }
}

__global__ __launch_bounds__(256) void fused_warp(
    const float* __restrict__ x,
    const float* __restrict__ paramP, const float* __restrict__ paramM,
    const float* __restrict__ gumbel_u, const float* __restrict__ eps,
    const int* __restrict__ idx,
    float* __restrict__ out, int N)
{
    __shared__ float smem[8];

    int b = blockIdx.z;
    int tid = threadIdx.y * 16 + threadIdx.x;

    // ---- per-block inverse-matrix computation (wave 0 only) ----
    if (tid < 64) {
        float dec = 0.f, sMv = 0.f;
        if (tid < 7) {
            int k = tid;
            int id = idx[b];
            float vP = paramP[k * N + id];
            float pP = 1.0f / (1.0f + expf(-vP));
            float l0 = logf(pP);
            float l1 = logf(1.0f - pP);
            float u0 = gumbel_u[(k * 16 + b) * 2 + 0];
            float u1 = gumbel_u[(k * 16 + b) * 2 + 1];
            float g0 = -logf(-logf(u0));
            float g1 = -logf(-logf(u1));
            dec = (l0 + g0 >= l1 + g1) ? 1.0f : 0.0f;  // argmax tie -> index 0
            float vM = paramM[k * N + id];
            float sig = 1.0f / (1.0f + expf(-vM));
            sMv = sig * eps[k * 16 + b];
        }
        float sP[7], sM[7];
#pragma unroll
        for (int k = 0; k < 7; ++k) {
            sP[k] = __shfl(dec, k, 64);
            sM[k] = __shfl(sMv, k, 64);
        }
        if (tid == 0) {
            float ang = sP[0] * sM[0] * 30.0f;
            float rad = ang * 0.017453292519943295f;
            float ca = cosf(rad), sa = sinf(rad);
            float sx = 1.0f + sP[5] * sM[5] * 0.5f;
            float sy = 1.0f + sP[6] * sM[6] * 0.5f;
            float sr00 = ca * sx, sr01 = sa * sy;
            float sr10 = -sa * sx, sr11 = ca * sy;
            float t0 = 128.0f - (sr00 + sr01) * 128.0f;
            float t1 = 128.0f - (sr10 + sr11) * 128.0f;
            float tx2 = 256.0f * sP[1] * sM[1] * 0.45f;
            float ty2 = 256.0f * sP[2] * sM[2] * 0.45f;
            float sh01 = sP[3] * sM[3] * 0.3f;
            float sh10 = sP[4] * sM[4] * 0.3f;
            float e0 = t0 + tx2, e1 = t1 + ty2;
            float a  = sr00 + sh01 * sr10;
            float bb = sr01 + sh01 * sr11;
            float txm = e0 + sh01 * e1;
            float c  = sh10 * sr00 + sr10;
            float d  = sh10 * sr01 + sr11;
            float tym = sh10 * e0 + e1;
            float det = a * d - bb * c;
            float rdet = 1.0f / det;
            smem[0] = d * rdet;
            smem[1] = -bb * rdet;
            smem[2] = (bb * tym - d * txm) * rdet;
            smem[3] = -c * rdet;
            smem[4] = a * rdet;
            smem[5] = (c * txm - a * tym) * rdet;
        }
    }
    __syncthreads();

    float m00 = smem[0], m01 = smem[1], m02 = smem[2];
    float m10 = smem[3], m11 = smem[4], m12 = smem[5];

    // ---- 8x8 wave tiling: wave w covers the 8x8 sub-tile (w&1, w>>1) of the
    // block's 16x16 tile; lane (lx,ly) = (lane&7, lane>>3). Compact source
    // footprint per wave -> ~2x fewer L1 line lookups per gather instruction.
    int wid  = tid >> 6;
    int lane = tid & 63;
    int lx = lane & 7, ly = lane >> 3;
    int j = blockIdx.x * 16 + ((wid & 1) * 8 + lx);
    int i = blockIdx.y * 16 + ((wid >> 1) * 8 + ly);

    const float* xb = x + b * 3 * 65536;

    float XA = (float)(4 * j + 1);
    float Y0 = (float)(4 * i + 1);
    float x0 = fmaf(m00, XA, fmaf(m01, Y0, m02));
    float y0 = fmaf(m10, XA, fmaf(m11, Y0, m12));
    float xs[4], ys[4];
    xs[0] = x0;        ys[0] = y0;
    xs[1] = x0 + m00;  ys[1] = y0 + m10;
    xs[2] = x0 + m01;  ys[2] = y0 + m11;
    xs[3] = xs[1] + m01; ys[3] = ys[1] + m11;

    Trip cx[4], ry[4];
#pragma unroll
    for (int s = 0; s < 4; ++s) {
        cx[s] = merged3(fminf(fmaxf(xs[s], 0.f), 1023.f));
        ry[s] = merged3(fminf(fmaxf(ys[s], 0.f), 1023.f));
    }

    int cbmin = min(min(cx[0].base, cx[1].base), min(cx[2].base, cx[3].base));
    int cbmax = max(max(cx[0].base, cx[1].base), max(cx[2].base, cx[3].base));
    int rbmin = min(min(ry[0].base, ry[1].base), min(ry[2].base, ry[3].base));
    int rbmax = max(max(ry[0].base, ry[1].base), max(ry[2].base, ry[3].base));

    float acc[3] = {0.f, 0.f, 0.f};

    if (((cbmax - cbmin) | (rbmax - rbmin)) <= 1) {
        // ---- fast path: single 4x4 union window, W = sum of 4 outer products
        float W[4][4];
#pragma unroll
        for (int s = 0; s < 4; ++s) {
            bool sc = (cx[s].base != cbmin);
            float C0 = sc ? 0.f : cx[s].w0;
            float C1 = sc ? cx[s].w0 : cx[s].w1;
            float C2 = sc ? cx[s].w1 : cx[s].w2;
            float C3 = sc ? cx[s].w2 : 0.f;
            bool sr = (ry[s].base != rbmin);
            float R0 = sr ? 0.f : ry[s].w0;
            float R1 = sr ? ry[s].w0 : ry[s].w1;
            float R2 = sr ? ry[s].w1 : ry[s].w2;
            float R3 = sr ? ry[s].w2 : 0.f;
            float C[4] = {C0, C1, C2, C3};
            float R[4] = {R0, R1, R2, R3};
            if (s == 0) {
#pragma unroll
                for (int r = 0; r < 4; ++r)
#pragma unroll
                    for (int c = 0; c < 4; ++c)
                        W[r][c] = R[r] * C[c];
            } else {
#pragma unroll
                for (int r = 0; r < 4; ++r)
#pragma unroll
                    for (int c = 0; c < 4; ++c)
                        W[r][c] = fmaf(R[r], C[c], W[r][c]);
            }
        }

        // right-edge safety: weights for columns > 255 are exactly zero, so
        // rotating right against base 252 is exact. shift <= 3.
        int base = cbmin;
        if (cbmin > 252) {
            int shift = cbmin - 252;
            base = 252;
            for (int s = 0; s < shift; ++s) {
#pragma unroll
                for (int r = 0; r < 4; ++r) {
                    W[r][3] = W[r][2]; W[r][2] = W[r][1];
                    W[r][1] = W[r][0]; W[r][0] = 0.f;
                }
            }
        }

        int e0 = rbmin * 256 + base;
        int e1 = min(rbmin + 1, 255) * 256 + base;  // rows past 255 carry zero
        int e2 = min(rbmin + 2, 255) * 256 + base;  //   weight; aliasing row
        int e3 = min(rbmin + 3, 255) * 256 + base;  //   255 is harmless
#pragma unroll
        for (int ch = 0; ch < 3; ++ch) {
            const float* pc = xb + ch * 65536;
            floatx4 L0 = load4(pc + e0);
            floatx4 L1 = load4(pc + e1);
            floatx4 L2 = load4(pc + e2);
            floatx4 L3 = load4(pc + e3);
            float s0 = fmaf(W[0][3], L0.w, fmaf(W[0][2], L0.z, fmaf(W[0][1], L0.y, W[0][0] * L0.x)));
            float s1 = fmaf(W[1][3], L1.w, fmaf(W[1][2], L1.z, fmaf(W[1][1], L1.y, W[1][0] * L1.x)));
            float s2 = fmaf(W[2][3], L2.w, fmaf(W[2][2], L2.z, fmaf(W[2][1], L2.y, W[2][0] * L2.x)));
            float s3 = fmaf(W[3][3], L3.w, fmaf(W[3][2], L3.z, fmaf(W[3][1], L3.y, W[3][0] * L3.x)));
            acc[ch] = (s0 + s1) + (s2 + s3);
        }
    } else {
        pair_accum(cx[0], cx[1], ry[0], ry[1], xb, acc);
        pair_accum(cx[2], cx[3], ry[2], ry[3], xb, acc);
    }

    int obase = ((b * 3) * 256 + i) * 256 + j;
    out[obase]          = 0.25f * acc[0];
    out[obase + 65536]  = 0.25f * acc[1];
    out[obase + 131072] = 0.25f * acc[2];
}

extern "C" void kernel_launch(void* const* d_in, const int* in_sizes, int n_in,
                              void* d_out, int out_size, void* d_ws, size_t ws_size,
                              hipStream_t stream) {
    const float* x      = (const float*)d_in[0];
    const float* paramP = (const float*)d_in[1];
    const float* paramM = (const float*)d_in[2];
    const float* gumbel = (const float*)d_in[3];
    const float* eps    = (const float*)d_in[4];
    const int*   idx    = (const int*)d_in[5];
    float* out = (float*)d_out;
    int N = in_sizes[1] / 7;

    hipLaunchKernelGGL(fused_warp, dim3(16, 16, 16), dim3(16, 16, 1), 0, stream,
                       x, paramP, paramM, gumbel, eps, idx, out, N);
}